// Round 2
// 1277.381 us; speedup vs baseline: 1.0798x; 1.0798x over previous
//
#include <hip/hip_runtime.h>
#include <hip/hip_bf16.h>
#include <hip/hip_fp8.h>
#include <cstdint>
#include <cstddef>

// Problem constants (from reference)
#define E_ 8
#define H_ 2048
#define I_ 5632
#define N1_ (2 * I_)
#define G_ 128
#define T_ 256
#define RPE 256            // fixed rows per expert (= T_, exact worst case)
#define SLOTS (E_ * RPE)   // 2048

typedef __attribute__((ext_vector_type(4))) float f32x4;
typedef __attribute__((ext_vector_type(8))) __bf16 bf16x8;

// Workspace layout (bytes). Total ~31.5 MB.
#define WS_CNT 0
#define WS_TOKEN 64
#define WS_GATE (64 + SLOTS * 4)
#define WS_A1 32768                    // SLOTS * H_ bf16 = 8 MB
#define WS_A2 (WS_A1 + SLOTS * H_ * 2) // SLOTS * I_ bf16 = 23 MB

__device__ __forceinline__ uint32_t pack_bf16x2(float a, float b) {
  union { float f; uint32_t u; } ua, ub;
  ua.f = a; ub.f = b;
  uint32_t ra = (ua.u + 0x7FFFu + ((ua.u >> 16) & 1u)) >> 16;         // RTNE bf16, low
  uint32_t rb = (ub.u + 0x7FFFu + ((ub.u >> 16) & 1u)) & 0xFFFF0000u; // high
  return ra | rb;
}

__device__ __forceinline__ float fp8_qdq1(float x) {
  x = fminf(fmaxf(x, -448.0f), 448.0f);
  __hip_fp8_e4m3 q(x);  // OCP e4m3fn on gfx950
  return (float)q;
}

// Workgroup barrier WITHOUT vmcnt drain: orders LDS traffic (lgkmcnt) only, so
// in-flight global prefetches (weights, A-frags) survive the barrier (T4).
// sched_barrier(0) fences keep the compiler from moving memory ops across.
__device__ __forceinline__ void block_sync_nodrain() {
  __builtin_amdgcn_sched_barrier(0);
  asm volatile("s_waitcnt lgkmcnt(0)" ::: "memory");
  __builtin_amdgcn_s_barrier();
  __builtin_amdgcn_sched_barrier(0);
}

// ---------------- routing: softmax top-2 -> fixed-capacity slot lists -------
__global__ void routing_kernel(const float* __restrict__ logits,
                               int* __restrict__ cnt,
                               int* __restrict__ token_of, float* __restrict__ gate_of) {
  __shared__ int s_cnt[E_];
  int t = threadIdx.x;  // one thread per token; blockDim.x == T_ == 256
  if (t < E_) s_cnt[t] = 0;
  __syncthreads();
  float l[E_];
#pragma unroll
  for (int e = 0; e < E_; e++) l[e] = logits[t * E_ + e];
  int i0 = 0;
#pragma unroll
  for (int e = 1; e < E_; e++) if (l[e] > l[i0]) i0 = e;  // ties -> lower idx
  int i1 = (i0 == 0) ? 1 : 0;
#pragma unroll
  for (int e = 0; e < E_; e++) if (e != i0 && l[e] > l[i1]) i1 = e;
  float g0 = 1.0f / (1.0f + expf(l[i1] - l[i0]));  // renormalized top-2 gates
  float g1 = 1.0f - g0;
  int s0 = atomicAdd(&s_cnt[i0], 1);
  int s1 = atomicAdd(&s_cnt[i1], 1);
  token_of[i0 * RPE + s0] = t;  gate_of[i0 * RPE + s0] = g0;
  token_of[i1 * RPE + s1] = t;  gate_of[i1 * RPE + s1] = g1;
  __syncthreads();
  if (t < E_) cnt[t] = s_cnt[t];
  for (int idx = t; idx < SLOTS; idx += 256) {
    int e = idx >> 8, r = idx & (RPE - 1);
    if (r >= s_cnt[e]) { token_of[idx] = 0; gate_of[idx] = 0.0f; }
  }
}

// ---------------- gather + fp8 qdq -> A1 (bf16, zero-padded rows) -----------
__global__ void gather_kernel(const float* __restrict__ hidden,
                              const float* __restrict__ is1,
                              const int* __restrict__ cnt,
                              const int* __restrict__ token_of,
                              __hip_bfloat16* __restrict__ A1) {
  int sg = blockIdx.x;
  int e = sg >> 8, r = sg & (RPE - 1);
  bool pad = (r >= cnt[e]);
  uint4 u;
  if (pad) {
    u.x = u.y = u.z = u.w = 0u;
  } else {
    int t = token_of[sg];
    float s1 = is1[e];
    const float4* hp = (const float4*)(hidden + (size_t)t * H_ + threadIdx.x * 8);
    float4 x0 = hp[0], x1 = hp[1];
    float q0 = fp8_qdq1(x0.x / s1), q1 = fp8_qdq1(x0.y / s1);
    float q2 = fp8_qdq1(x0.z / s1), q3 = fp8_qdq1(x0.w / s1);
    float q4 = fp8_qdq1(x1.x / s1), q5 = fp8_qdq1(x1.y / s1);
    float q6 = fp8_qdq1(x1.z / s1), q7 = fp8_qdq1(x1.w / s1);
    u.x = pack_bf16x2(q0, q1); u.y = pack_bf16x2(q2, q3);
    u.z = pack_bf16x2(q4, q5); u.w = pack_bf16x2(q6, q7);
  }
  ((uint4*)(A1 + (size_t)sg * H_))[threadIdx.x] = u;
}

// ---------------- fc1: LDS-staged pipelined MFMA GEMM + fused SwiGLU --------
// Block = 4 waves. INTERLEAVED M map: wave w owns chunks {w, w+4, w+8, w+12}
// (chunk c = rows c*16..c*16+15), so for cnt≈64 the 4 active chunks spread one
// per wave/SIMD. Chunks with base row >= cnt are skipped entirely (no A loads,
// no MFMA, no epilogue) — fc2 uses the identical map so those A2 rows are
// never read. Raw barrier (no vmcnt drain) keeps depth-2 prefetch in flight.
__global__ __launch_bounds__(256) void fc1_kernel(
    const int* __restrict__ w1, const float* __restrict__ w1s,
    const float* __restrict__ is1v, const float* __restrict__ is2v,
    const int* __restrict__ cnt,
    const __hip_bfloat16* __restrict__ A1, __hip_bfloat16* __restrict__ A2) {
  __shared__ __hip_bfloat16 Bt[2][4][64][8];  // 8 KB
  const int e = blockIdx.y;
  const int j0 = blockIdx.x * 32;
  const int tid = threadIdx.x;
  const int wave = tid >> 6, lane = tid & 63;
  const int lm = lane & 15, kq = lane >> 4;
  const int sn = lane;          // staging: logical n in [0,64)
  const int kb4 = wave * 4;     // staging: k = kb4 + 16*g + c
  const int gcol = (sn < 32) ? (j0 + sn) : (I_ + j0 + (sn - 32));
  const int* wp = w1 + (size_t)e * H_ * N1_ + gcol;
  const float* sbase = w1s + (size_t)e * (H_ / G_) * N1_ + gcol;
  const __hip_bfloat16* abase = A1 + (size_t)e * RPE * H_;

  // active chunk count for this wave: chunks mj*4+wave with (mj*4+wave)*16 < cnt
  const int C16 = (cnt[e] + 15) >> 4;
  int nact = (C16 - wave + 3) >> 2;
  if (nact < 0) nact = 0;

  f32x4 acc[4][4];
#pragma unroll
  for (int a = 0; a < 4; a++)
#pragma unroll
    for (int b = 0; b < 4; b++) acc[a][b] = (f32x4){0.f, 0.f, 0.f, 0.f};

  // prologue: load ks=0 weights, stage into buf0; load ks=1 weights
  int wA[8], wB[8];
  float scA = sbase[0], scB = scA;  // ks=0,1 are in group 0
#pragma unroll
  for (int g = 0; g < 2; g++)
#pragma unroll
    for (int c = 0; c < 4; c++)
      wA[g * 4 + c] = __builtin_nontemporal_load(wp + (size_t)(kb4 + 16 * g + c) * N1_);
#pragma unroll
  for (int g = 0; g < 2; g++) {
    uint32_t p0 = pack_bf16x2((float)wA[g * 4 + 0] * scA, (float)wA[g * 4 + 1] * scA);
    uint32_t p1 = pack_bf16x2((float)wA[g * 4 + 2] * scA, (float)wA[g * 4 + 3] * scA);
    *(uint2*)&Bt[0][(wave >> 1) + 2 * g][sn][(wave & 1) * 4] = make_uint2(p0, p1);
  }
  wp += (size_t)32 * N1_;
#pragma unroll
  for (int g = 0; g < 2; g++)
#pragma unroll
    for (int c = 0; c < 4; c++)
      wB[g * 4 + c] = __builtin_nontemporal_load(wp + (size_t)(kb4 + 16 * g + c) * N1_);
  wp += (size_t)32 * N1_;  // -> ks=2

  // A prefetch for ks=0 (active chunks only)
  const __hip_bfloat16* aptr[4];
  uint4 afr[4];
#pragma unroll
  for (int mj = 0; mj < 4; mj++) {
    aptr[mj] = abase + (size_t)((mj * 4 + wave) * 16 + lm) * H_ + kq * 8;
    if (mj < nact) afr[mj] = *(const uint4*)aptr[mj];
  }

  block_sync_nodrain();

  for (int ks = 0; ks < 64; ks++) {
    const int buf = ks & 1;
    int wC[8]; float scC = scB;
    if (ks + 2 < 64) {
      if (((ks + 2) & 3) == 0) scC = sbase[(size_t)((ks + 2) >> 2) * N1_];
#pragma unroll
      for (int g = 0; g < 2; g++)
#pragma unroll
        for (int c = 0; c < 4; c++)
          wC[g * 4 + c] = __builtin_nontemporal_load(wp + (size_t)(kb4 + 16 * g + c) * N1_);
    }
    uint4 anx[4];
    if (ks + 1 < 64) {
#pragma unroll
      for (int mj = 0; mj < 4; mj++)
        if (mj < nact) anx[mj] = *(const uint4*)(aptr[mj] + (ks + 1) * 32);
    }
    if (nact == 4) {
#pragma unroll
      for (int f = 0; f < 4; f++) {
        union { uint4 u; bf16x8 v; } bu;
        bu.u = *(const uint4*)&Bt[buf][kq][f * 16 + lm][0];
#pragma unroll
        for (int mj = 0; mj < 4; mj++) {
          union { uint4 u; bf16x8 v; } au;
          au.u = afr[mj];
          acc[mj][f] = __builtin_amdgcn_mfma_f32_16x16x32_bf16(au.v, bu.v, acc[mj][f], 0, 0, 0);
        }
      }
    } else if (nact > 0) {
#pragma unroll
      for (int f = 0; f < 4; f++) {
        union { uint4 u; bf16x8 v; } bu;
        bu.u = *(const uint4*)&Bt[buf][kq][f * 16 + lm][0];
#pragma unroll
        for (int mj = 0; mj < 4; mj++) {
          if (mj < nact) {
            union { uint4 u; bf16x8 v; } au;
            au.u = afr[mj];
            acc[mj][f] = __builtin_amdgcn_mfma_f32_16x16x32_bf16(au.v, bu.v, acc[mj][f], 0, 0, 0);
          }
        }
      }
    }
    if (ks + 1 < 64) {
#pragma unroll
      for (int g = 0; g < 2; g++) {
        uint32_t p0 = pack_bf16x2((float)wB[g * 4 + 0] * scB, (float)wB[g * 4 + 1] * scB);
        uint32_t p1 = pack_bf16x2((float)wB[g * 4 + 2] * scB, (float)wB[g * 4 + 3] * scB);
        *(uint2*)&Bt[buf ^ 1][(wave >> 1) + 2 * g][sn][(wave & 1) * 4] = make_uint2(p0, p1);
      }
    }
    block_sync_nodrain();
#pragma unroll
    for (int i = 0; i < 8; i++) wB[i] = wC[i];
    scB = scC;
#pragma unroll
    for (int mj = 0; mj < 4; mj++) afr[mj] = anx[mj];
    wp += (size_t)32 * N1_;
  }

  // epilogue: SwiGLU in registers (wave holds matching up f and gate f+2 cols)
  const float s1 = is1v[e], s2 = is2v[e];
  __hip_bfloat16* a2base = A2 + (size_t)(e * RPE) * I_ + j0;
#pragma unroll
  for (int mj = 0; mj < 4; mj++) {
    if (mj < nact) {
      int mrow = (mj * 4 + wave) * 16 + kq * 4;
#pragma unroll
      for (int r = 0; r < 4; r++) {
#pragma unroll
        for (int f = 0; f < 2; f++) {
          float up = acc[mj][f][r] * s1;
          float gt = acc[mj][f + 2][r] * s1;
          float h = up * (gt / (1.0f + expf(-gt)));  // up * silu(gate)
          float q = fp8_qdq1(h / s2);
          a2base[(size_t)(mrow + r) * I_ + f * 16 + lm] = __float2bfloat16(q);
        }
      }
    }
  }
}

// ---------------- fc2: same structure, split-K x4, atomic scatter-add -------
__global__ __launch_bounds__(256) void fc2_kernel(
    const int* __restrict__ w2, const float* __restrict__ w2s,
    const float* __restrict__ is2v, const int* __restrict__ cnt,
    const int* __restrict__ token_of, const float* __restrict__ gate_of,
    const __hip_bfloat16* __restrict__ A2, float* __restrict__ out) {
  __shared__ __hip_bfloat16 Bt[2][4][64][8];  // 8 KB
  const int e = blockIdx.y;
  const int n0 = blockIdx.x * 64;
  const int z = blockIdx.z;       // 4 slices * 44 k-steps = 176 = I_/32
  const int tid = threadIdx.x;
  const int wave = tid >> 6, lane = tid & 63;
  const int lm = lane & 15, kq = lane >> 4;
  const int sn = lane;
  const int kb4 = wave * 4;
  const int gcol = n0 + sn;
  const int* wp = w2 + (size_t)e * I_ * H_ + (size_t)(z * 44 * 32) * H_ + gcol;
  const float* sbase = w2s + (size_t)e * (I_ / G_) * H_ + gcol;
  const __hip_bfloat16* abase = A2 + (size_t)e * RPE * I_;

  const int c_n = cnt[e];
  const int C16 = (c_n + 15) >> 4;
  int nact = (C16 - wave + 3) >> 2;  // same interleaved chunk map as fc1
  if (nact < 0) nact = 0;

  f32x4 acc[4][4];
#pragma unroll
  for (int a = 0; a < 4; a++)
#pragma unroll
    for (int b = 0; b < 4; b++) acc[a][b] = (f32x4){0.f, 0.f, 0.f, 0.f};

  int wA[8], wB[8];
  float scA = sbase[(size_t)(z * 11) * H_], scB = scA;
#pragma unroll
  for (int g = 0; g < 2; g++)
#pragma unroll
    for (int c = 0; c < 4; c++)
      wA[g * 4 + c] = __builtin_nontemporal_load(wp + (size_t)(kb4 + 16 * g + c) * H_);
#pragma unroll
  for (int g = 0; g < 2; g++) {
    uint32_t p0 = pack_bf16x2((float)wA[g * 4 + 0] * scA, (float)wA[g * 4 + 1] * scA);
    uint32_t p1 = pack_bf16x2((float)wA[g * 4 + 2] * scA, (float)wA[g * 4 + 3] * scA);
    *(uint2*)&Bt[0][(wave >> 1) + 2 * g][sn][(wave & 1) * 4] = make_uint2(p0, p1);
  }
  wp += (size_t)32 * H_;
#pragma unroll
  for (int g = 0; g < 2; g++)
#pragma unroll
    for (int c = 0; c < 4; c++)
      wB[g * 4 + c] = __builtin_nontemporal_load(wp + (size_t)(kb4 + 16 * g + c) * H_);
  wp += (size_t)32 * H_;

  const __hip_bfloat16* aptr[4];
  uint4 afr[4];
#pragma unroll
  for (int mj = 0; mj < 4; mj++) {
    aptr[mj] = abase + (size_t)((mj * 4 + wave) * 16 + lm) * I_ + (size_t)z * 44 * 32 + kq * 8;
    if (mj < nact) afr[mj] = *(const uint4*)aptr[mj];
  }

  block_sync_nodrain();

  for (int ks = 0; ks < 44; ks++) {
    const int buf = ks & 1;
    int wC[8]; float scC = scB;
    if (ks + 2 < 44) {
      if (((ks + 2) & 3) == 0) scC = sbase[(size_t)(z * 11 + ((ks + 2) >> 2)) * H_];
#pragma unroll
      for (int g = 0; g < 2; g++)
#pragma unroll
        for (int c = 0; c < 4; c++)
          wC[g * 4 + c] = __builtin_nontemporal_load(wp + (size_t)(kb4 + 16 * g + c) * H_);
    }
    uint4 anx[4];
    if (ks + 1 < 44) {
#pragma unroll
      for (int mj = 0; mj < 4; mj++)
        if (mj < nact) anx[mj] = *(const uint4*)(aptr[mj] + (ks + 1) * 32);
    }
    if (nact == 4) {
#pragma unroll
      for (int f = 0; f < 4; f++) {
        union { uint4 u; bf16x8 v; } bu;
        bu.u = *(const uint4*)&Bt[buf][kq][f * 16 + lm][0];
#pragma unroll
        for (int mj = 0; mj < 4; mj++) {
          union { uint4 u; bf16x8 v; } au;
          au.u = afr[mj];
          acc[mj][f] = __builtin_amdgcn_mfma_f32_16x16x32_bf16(au.v, bu.v, acc[mj][f], 0, 0, 0);
        }
      }
    } else if (nact > 0) {
#pragma unroll
      for (int f = 0; f < 4; f++) {
        union { uint4 u; bf16x8 v; } bu;
        bu.u = *(const uint4*)&Bt[buf][kq][f * 16 + lm][0];
#pragma unroll
        for (int mj = 0; mj < 4; mj++) {
          if (mj < nact) {
            union { uint4 u; bf16x8 v; } au;
            au.u = afr[mj];
            acc[mj][f] = __builtin_amdgcn_mfma_f32_16x16x32_bf16(au.v, bu.v, acc[mj][f], 0, 0, 0);
          }
        }
      }
    }
    if (ks + 1 < 44) {
#pragma unroll
      for (int g = 0; g < 2; g++) {
        uint32_t p0 = pack_bf16x2((float)wB[g * 4 + 0] * scB, (float)wB[g * 4 + 1] * scB);
        uint32_t p1 = pack_bf16x2((float)wB[g * 4 + 2] * scB, (float)wB[g * 4 + 3] * scB);
        *(uint2*)&Bt[buf ^ 1][(wave >> 1) + 2 * g][sn][(wave & 1) * 4] = make_uint2(p0, p1);
      }
    }
    block_sync_nodrain();
#pragma unroll
    for (int i = 0; i < 8; i++) wB[i] = wC[i];
    scB = scC;
#pragma unroll
    for (int mj = 0; mj < 4; mj++) afr[mj] = anx[mj];
    wp += (size_t)32 * H_;
  }

  const float s2 = is2v[e];
#pragma unroll
  for (int mj = 0; mj < 4; mj++) {
    if (mj < nact) {
      int sl0 = (mj * 4 + wave) * 16 + kq * 4;
#pragma unroll
      for (int r = 0; r < 4; r++) {
        int slot = sl0 + r;
        if (slot < c_n) {
          int t = token_of[e * RPE + slot];
          float gv = gate_of[e * RPE + slot] * s2;
#pragma unroll
          for (int f = 0; f < 4; f++)
            atomicAdd(out + (size_t)t * H_ + n0 + f * 16 + lm, acc[mj][f][r] * gv);
        }
      }
    }
  }
}

extern "C" void kernel_launch(void* const* d_in, const int* in_sizes, int n_in,
                              void* d_out, int out_size, void* d_ws, size_t ws_size,
                              hipStream_t stream) {
  const float* hidden = (const float*)d_in[0];
  const float* logits = (const float*)d_in[1];
  const int* w1 = (const int*)d_in[2];
  const int* w2 = (const int*)d_in[3];
  const float* w1s = (const float*)d_in[4];
  const float* w2s = (const float*)d_in[5];
  const float* is1 = (const float*)d_in[6];
  const float* is2 = (const float*)d_in[7];
  float* out = (float*)d_out;
  char* ws = (char*)d_ws;
  int* cnt = (int*)(ws + WS_CNT);
  int* token_of = (int*)(ws + WS_TOKEN);
  float* gate_of = (float*)(ws + WS_GATE);
  __hip_bfloat16* A1 = (__hip_bfloat16*)(ws + WS_A1);
  __hip_bfloat16* A2 = (__hip_bfloat16*)(ws + WS_A2);

  hipMemsetAsync(d_out, 0, (size_t)T_ * H_ * sizeof(float), stream);
  routing_kernel<<<1, 256, 0, stream>>>(logits, cnt, token_of, gate_of);
  gather_kernel<<<SLOTS, 256, 0, stream>>>(hidden, is1, cnt, token_of, A1);
  fc1_kernel<<<dim3(I_ / 32, E_), 256, 0, stream>>>(w1, w1s, is1, is2, cnt, A1, A2);
  fc2_kernel<<<dim3(H_ / 64, E_, 4), 256, 0, stream>>>(w2, w2s, is2, cnt, token_of,
                                                       gate_of, A2, out);
}

// Round 3
// 1241.939 us; speedup vs baseline: 1.1107x; 1.0285x over previous
//
#include <hip/hip_runtime.h>
#include <hip/hip_bf16.h>
#include <hip/hip_fp8.h>
#include <cstdint>
#include <cstddef>

// Problem constants (from reference)
#define E_ 8
#define H_ 2048
#define I_ 5632
#define N1_ (2 * I_)
#define G_ 128
#define T_ 256
#define RPE 256            // fixed rows per expert (= T_, exact worst case)
#define SLOTS (E_ * RPE)   // 2048

typedef __attribute__((ext_vector_type(4))) float f32x4;
typedef __attribute__((ext_vector_type(8))) __bf16 bf16x8;
typedef __attribute__((ext_vector_type(2))) int i32x2;

// Workspace layout (bytes). Total ~31.5 MB.
#define WS_CNT 0
#define WS_TOKEN 64
#define WS_GATE (64 + SLOTS * 4)
#define WS_A1 32768                    // SLOTS * H_ bf16 = 8 MB
#define WS_A2 (WS_A1 + SLOTS * H_ * 2) // SLOTS * I_ bf16 = 23 MB

__device__ __forceinline__ uint32_t pack_bf16x2(float a, float b) {
  union { float f; uint32_t u; } ua, ub;
  ua.f = a; ub.f = b;
  uint32_t ra = (ua.u + 0x7FFFu + ((ua.u >> 16) & 1u)) >> 16;         // RTNE bf16, low
  uint32_t rb = (ub.u + 0x7FFFu + ((ub.u >> 16) & 1u)) & 0xFFFF0000u; // high
  return ra | rb;
}

__device__ __forceinline__ float fp8_qdq1(float x) {
  x = fminf(fmaxf(x, -448.0f), 448.0f);
  __hip_fp8_e4m3 q(x);  // OCP e4m3fn on gfx950
  return (float)q;
}

// Workgroup barrier WITHOUT vmcnt drain: orders LDS traffic (lgkmcnt) only, so
// in-flight global prefetches (weights, A-frags) survive the barrier (T4).
__device__ __forceinline__ void block_sync_nodrain() {
  __builtin_amdgcn_sched_barrier(0);
  asm volatile("s_waitcnt lgkmcnt(0)" ::: "memory");
  __builtin_amdgcn_s_barrier();
  __builtin_amdgcn_sched_barrier(0);
}

// Issue 4 dwordx2 weight loads: thread's 2-col x 4-k patch at k-step m.
// wpt is pre-offset by (kg*4) rows + gc2 col; ldN = row stride in ints.
__device__ __forceinline__ void wissue(const int* __restrict__ wpt, size_t ldN, int m,
                                       i32x2 wv[4]) {
#pragma unroll
  for (int c = 0; c < 4; ++c)
    wv[c] = __builtin_nontemporal_load(
        reinterpret_cast<const i32x2*>(wpt + ((size_t)m * 32 + c) * ldN));
}

// Dequant + pack + LDS write (two b64 writes; LDS layout identical to prior rounds:
// Bt[kqw][n][slot] = bf16 of W[k0 + kqw*8 + slot][gcol(n)]).
__device__ __forceinline__ void wstage(__hip_bfloat16 (*Btb)[64][8], int kqw, int n0, int h4,
                                       const i32x2 wv[4], float2 sc) {
  uint32_t a0 = pack_bf16x2((float)wv[0].x * sc.x, (float)wv[1].x * sc.x);
  uint32_t a1 = pack_bf16x2((float)wv[2].x * sc.x, (float)wv[3].x * sc.x);
  uint32_t b0 = pack_bf16x2((float)wv[0].y * sc.y, (float)wv[1].y * sc.y);
  uint32_t b1 = pack_bf16x2((float)wv[2].y * sc.y, (float)wv[3].y * sc.y);
  *(uint2*)&Btb[kqw][n0][h4] = make_uint2(a0, a1);
  *(uint2*)&Btb[kqw][n0 + 1][h4] = make_uint2(b0, b1);
}

__device__ __forceinline__ void aissue(const __hip_bfloat16* const aptr[4], int m, int nact,
                                       uint4 av[4]) {
#pragma unroll
  for (int mj = 0; mj < 4; ++mj)
    if (mj < nact) av[mj] = *(const uint4*)(aptr[mj] + (size_t)m * 32);
}

__device__ __forceinline__ void do_mfma(const __hip_bfloat16 (*Btb)[64][8], int kq, int lm,
                                        int nact, const uint4 afr[4], f32x4 acc[4][4]) {
#pragma unroll
  for (int f = 0; f < 4; ++f) {
    union { uint4 u; bf16x8 v; } bu;
    bu.u = *(const uint4*)&Btb[kq][f * 16 + lm][0];
#pragma unroll
    for (int mj = 0; mj < 4; ++mj)
      if (mj < nact) {
        union { uint4 u; bf16x8 v; } au;
        au.u = afr[mj];
        acc[mj][f] = __builtin_amdgcn_mfma_f32_16x16x32_bf16(au.v, bu.v, acc[mj][f], 0, 0, 0);
      }
  }
}

// ---------------- routing: softmax top-2 -> fixed-capacity slot lists -------
__global__ void routing_kernel(const float* __restrict__ logits,
                               int* __restrict__ cnt,
                               int* __restrict__ token_of, float* __restrict__ gate_of) {
  __shared__ int s_cnt[E_];
  int t = threadIdx.x;  // one thread per token; blockDim.x == T_ == 256
  if (t < E_) s_cnt[t] = 0;
  __syncthreads();
  float l[E_];
#pragma unroll
  for (int e = 0; e < E_; e++) l[e] = logits[t * E_ + e];
  int i0 = 0;
#pragma unroll
  for (int e = 1; e < E_; e++) if (l[e] > l[i0]) i0 = e;  // ties -> lower idx
  int i1 = (i0 == 0) ? 1 : 0;
#pragma unroll
  for (int e = 0; e < E_; e++) if (e != i0 && l[e] > l[i1]) i1 = e;
  float g0 = 1.0f / (1.0f + expf(l[i1] - l[i0]));  // renormalized top-2 gates
  float g1 = 1.0f - g0;
  int s0 = atomicAdd(&s_cnt[i0], 1);
  int s1 = atomicAdd(&s_cnt[i1], 1);
  token_of[i0 * RPE + s0] = t;  gate_of[i0 * RPE + s0] = g0;
  token_of[i1 * RPE + s1] = t;  gate_of[i1 * RPE + s1] = g1;
  __syncthreads();
  if (t < E_) cnt[t] = s_cnt[t];
  for (int idx = t; idx < SLOTS; idx += 256) {
    int e = idx >> 8, r = idx & (RPE - 1);
    if (r >= s_cnt[e]) { token_of[idx] = 0; gate_of[idx] = 0.0f; }
  }
}

// ---------------- gather + fp8 qdq -> A1 (bf16, zero-padded rows) -----------
__global__ void gather_kernel(const float* __restrict__ hidden,
                              const float* __restrict__ is1,
                              const int* __restrict__ cnt,
                              const int* __restrict__ token_of,
                              __hip_bfloat16* __restrict__ A1) {
  int sg = blockIdx.x;
  int e = sg >> 8, r = sg & (RPE - 1);
  bool pad = (r >= cnt[e]);
  uint4 u;
  if (pad) {
    u.x = u.y = u.z = u.w = 0u;
  } else {
    int t = token_of[sg];
    float s1 = is1[e];
    const float4* hp = (const float4*)(hidden + (size_t)t * H_ + threadIdx.x * 8);
    float4 x0 = hp[0], x1 = hp[1];
    float q0 = fp8_qdq1(x0.x / s1), q1 = fp8_qdq1(x0.y / s1);
    float q2 = fp8_qdq1(x0.z / s1), q3 = fp8_qdq1(x0.w / s1);
    float q4 = fp8_qdq1(x1.x / s1), q5 = fp8_qdq1(x1.y / s1);
    float q6 = fp8_qdq1(x1.z / s1), q7 = fp8_qdq1(x1.w / s1);
    u.x = pack_bf16x2(q0, q1); u.y = pack_bf16x2(q2, q3);
    u.z = pack_bf16x2(q4, q5); u.w = pack_bf16x2(q6, q7);
  }
  ((uint4*)(A1 + (size_t)sg * H_))[threadIdx.x] = u;
}

// ---------------- fc1: unroll-2 pipelined MFMA GEMM + fused SwiGLU ---------
// Staging map: thread t owns n-pair np=t&31 (2 cols) x 4 k-rows (kg=t>>5);
// 4 dwordx2 loads per k-step (fully coalesced), 2 b64 LDS writes. Unroll-2
// with named reg sets (wv0/wv1, av0/av1): no reg-copies, loads get a full
// k-step of slack across the no-drain barrier.
__global__ __launch_bounds__(256) void fc1_kernel(
    const int* __restrict__ w1, const float* __restrict__ w1s,
    const float* __restrict__ is1v, const float* __restrict__ is2v,
    const int* __restrict__ cnt,
    const __hip_bfloat16* __restrict__ A1, __hip_bfloat16* __restrict__ A2) {
  __shared__ __hip_bfloat16 Bt[2][4][64][8];  // 8 KB
  const int e = blockIdx.y;
  const int j0 = blockIdx.x * 32;
  const int tid = threadIdx.x;
  const int wave = tid >> 6, lane = tid & 63;
  const int lm = lane & 15, kq = lane >> 4;
  // staging map
  const int np = tid & 31, kg = tid >> 5;
  const int kqw = kg >> 1, h4 = (kg & 1) * 4;
  const int n0s = np * 2;
  const int gc2 = (n0s < 32) ? (j0 + n0s) : (I_ + j0 + (n0s - 32));
  const int* wpt = w1 + (size_t)e * H_ * N1_ + (size_t)(kg * 4) * N1_ + gc2;
  const float* spt = w1s + (size_t)e * (H_ / G_) * N1_ + gc2;
  const __hip_bfloat16* abase = A1 + (size_t)e * RPE * H_;

  const int C16 = (cnt[e] + 15) >> 4;
  int nact = (C16 - wave + 3) >> 2;
  if (nact < 0) nact = 0;

  f32x4 acc[4][4];
#pragma unroll
  for (int a = 0; a < 4; a++)
#pragma unroll
    for (int b = 0; b < 4; b++) acc[a][b] = (f32x4){0.f, 0.f, 0.f, 0.f};

  const __hip_bfloat16* aptr[4];
#pragma unroll
  for (int mj = 0; mj < 4; mj++)
    aptr[mj] = abase + (size_t)((mj * 4 + wave) * 16 + lm) * H_ + kq * 8;

  // prologue
  i32x2 wv0[4], wv1[4];
  uint4 av0[4], av1[4];
  float2 sc0 = *(const float2*)spt;  // group 0
  float2 sc1 = sc0;
  wissue(wpt, N1_, 0, wv0);
  wissue(wpt, N1_, 1, wv1);
  aissue(aptr, 0, nact, av1);
  wstage(Bt[0], kqw, n0s, h4, wv0, sc0);
  block_sync_nodrain();

  for (int i = 0; i < 31; ++i) {
    const int ks = 2 * i;
    // even: process ks on buf0 with av1
    if (((ks + 2) & 3) == 0) sc0 = *(const float2*)(spt + (size_t)((ks + 2) >> 2) * N1_);
    wissue(wpt, N1_, ks + 2, wv0);
    aissue(aptr, ks + 1, nact, av0);
    do_mfma(Bt[0], kq, lm, nact, av1, acc);
    wstage(Bt[1], kqw, n0s, h4, wv1, sc1);
    block_sync_nodrain();
    // odd: process ks+1 on buf1 with av0
    if (((ks + 3) & 3) == 1) sc1 = *(const float2*)(spt + (size_t)((ks + 3) >> 2) * N1_);
    wissue(wpt, N1_, ks + 3, wv1);
    aissue(aptr, ks + 2, nact, av1);
    do_mfma(Bt[1], kq, lm, nact, av0, acc);
    wstage(Bt[0], kqw, n0s, h4, wv0, sc0);
    block_sync_nodrain();
  }
  // peeled ks=62,63
  aissue(aptr, 63, nact, av0);
  do_mfma(Bt[0], kq, lm, nact, av1, acc);
  wstage(Bt[1], kqw, n0s, h4, wv1, sc1);
  block_sync_nodrain();
  do_mfma(Bt[1], kq, lm, nact, av0, acc);

  // epilogue: SwiGLU in registers
  const float s1 = is1v[e], s2 = is2v[e];
  __hip_bfloat16* a2base = A2 + (size_t)(e * RPE) * I_ + j0;
#pragma unroll
  for (int mj = 0; mj < 4; mj++) {
    if (mj < nact) {
      int mrow = (mj * 4 + wave) * 16 + kq * 4;
#pragma unroll
      for (int r = 0; r < 4; r++) {
#pragma unroll
        for (int f = 0; f < 2; f++) {
          float up = acc[mj][f][r] * s1;
          float gt = acc[mj][f + 2][r] * s1;
          float h = up * (gt / (1.0f + expf(-gt)));  // up * silu(gate)
          float q = fp8_qdq1(h / s2);
          a2base[(size_t)(mrow + r) * I_ + f * 16 + lm] = __float2bfloat16(q);
        }
      }
    }
  }
}

// ---------------- fc2: same structure, split-K x4, atomic scatter-add -------
__global__ __launch_bounds__(256) void fc2_kernel(
    const int* __restrict__ w2, const float* __restrict__ w2s,
    const float* __restrict__ is2v, const int* __restrict__ cnt,
    const int* __restrict__ token_of, const float* __restrict__ gate_of,
    const __hip_bfloat16* __restrict__ A2, float* __restrict__ out) {
  __shared__ __hip_bfloat16 Bt[2][4][64][8];  // 8 KB
  const int e = blockIdx.y;
  const int n0 = blockIdx.x * 64;
  const int z = blockIdx.z;       // 4 slices * 11 groups * 4 k-steps = 176 = I_/32
  const int tid = threadIdx.x;
  const int wave = tid >> 6, lane = tid & 63;
  const int lm = lane & 15, kq = lane >> 4;
  const int np = tid & 31, kg = tid >> 5;
  const int kqw = kg >> 1, h4 = (kg & 1) * 4;
  const int n0s = np * 2;
  const int gc2 = n0 + n0s;
  const int z11 = z * 11;
  const int* wpt = w2 + (size_t)e * I_ * H_ + (size_t)(z * 44 * 32 + kg * 4) * H_ + gc2;
  const float* spt = w2s + (size_t)e * (I_ / G_) * H_ + gc2;
  const __hip_bfloat16* abase = A2 + (size_t)e * RPE * I_;

  const int c_n = cnt[e];
  const int C16 = (c_n + 15) >> 4;
  int nact = (C16 - wave + 3) >> 2;  // same interleaved chunk map as fc1
  if (nact < 0) nact = 0;

  f32x4 acc[4][4];
#pragma unroll
  for (int a = 0; a < 4; a++)
#pragma unroll
    for (int b = 0; b < 4; b++) acc[a][b] = (f32x4){0.f, 0.f, 0.f, 0.f};

  const __hip_bfloat16* aptr[4];
#pragma unroll
  for (int mj = 0; mj < 4; mj++)
    aptr[mj] = abase + (size_t)((mj * 4 + wave) * 16 + lm) * I_ + (size_t)z * 44 * 32 + kq * 8;

  // prologue
  i32x2 wv0[4], wv1[4];
  uint4 av0[4], av1[4];
  float2 sc0 = *(const float2*)(spt + (size_t)z11 * H_);
  float2 sc1 = sc0;
  wissue(wpt, H_, 0, wv0);
  wissue(wpt, H_, 1, wv1);
  aissue(aptr, 0, nact, av1);
  wstage(Bt[0], kqw, n0s, h4, wv0, sc0);
  block_sync_nodrain();

  for (int i = 0; i < 21; ++i) {
    const int ks = 2 * i;
    if (((ks + 2) & 3) == 0)
      sc0 = *(const float2*)(spt + (size_t)(z11 + ((ks + 2) >> 2)) * H_);
    wissue(wpt, H_, ks + 2, wv0);
    aissue(aptr, ks + 1, nact, av0);
    do_mfma(Bt[0], kq, lm, nact, av1, acc);
    wstage(Bt[1], kqw, n0s, h4, wv1, sc1);
    block_sync_nodrain();
    if (((ks + 3) & 3) == 1)
      sc1 = *(const float2*)(spt + (size_t)(z11 + ((ks + 3) >> 2)) * H_);
    wissue(wpt, H_, ks + 3, wv1);
    aissue(aptr, ks + 2, nact, av1);
    do_mfma(Bt[1], kq, lm, nact, av0, acc);
    wstage(Bt[0], kqw, n0s, h4, wv0, sc0);
    block_sync_nodrain();
  }
  // peeled ks=42,43
  aissue(aptr, 43, nact, av0);
  do_mfma(Bt[0], kq, lm, nact, av1, acc);
  wstage(Bt[1], kqw, n0s, h4, wv1, sc1);
  block_sync_nodrain();
  do_mfma(Bt[1], kq, lm, nact, av0, acc);

  const float s2 = is2v[e];
#pragma unroll
  for (int mj = 0; mj < 4; mj++) {
    if (mj < nact) {
      int sl0 = (mj * 4 + wave) * 16 + kq * 4;
#pragma unroll
      for (int r = 0; r < 4; r++) {
        int slot = sl0 + r;
        if (slot < c_n) {
          int t = token_of[e * RPE + slot];
          float gv = gate_of[e * RPE + slot] * s2;
#pragma unroll
          for (int f = 0; f < 4; f++)
            atomicAdd(out + (size_t)t * H_ + n0 + f * 16 + lm, acc[mj][f][r] * gv);
        }
      }
    }
  }
}

extern "C" void kernel_launch(void* const* d_in, const int* in_sizes, int n_in,
                              void* d_out, int out_size, void* d_ws, size_t ws_size,
                              hipStream_t stream) {
  const float* hidden = (const float*)d_in[0];
  const float* logits = (const float*)d_in[1];
  const int* w1 = (const int*)d_in[2];
  const int* w2 = (const int*)d_in[3];
  const float* w1s = (const float*)d_in[4];
  const float* w2s = (const float*)d_in[5];
  const float* is1 = (const float*)d_in[6];
  const float* is2 = (const float*)d_in[7];
  float* out = (float*)d_out;
  char* ws = (char*)d_ws;
  int* cnt = (int*)(ws + WS_CNT);
  int* token_of = (int*)(ws + WS_TOKEN);
  float* gate_of = (float*)(ws + WS_GATE);
  __hip_bfloat16* A1 = (__hip_bfloat16*)(ws + WS_A1);
  __hip_bfloat16* A2 = (__hip_bfloat16*)(ws + WS_A2);

  hipMemsetAsync(d_out, 0, (size_t)T_ * H_ * sizeof(float), stream);
  routing_kernel<<<1, 256, 0, stream>>>(logits, cnt, token_of, gate_of);
  gather_kernel<<<SLOTS, 256, 0, stream>>>(hidden, is1, cnt, token_of, A1);
  fc1_kernel<<<dim3(I_ / 32, E_), 256, 0, stream>>>(w1, w1s, is1, is2, cnt, A1, A2);
  fc2_kernel<<<dim3(H_ / 64, E_, 4), 256, 0, stream>>>(w2, w2s, is2, cnt, token_of,
                                                       gate_of, A2, out);
}